// Round 12
// baseline (115.913 us; speedup 1.0000x reference)
//
#include <hip/hip_runtime.h>
#include <hip/hip_bf16.h>
#include <stdint.h>

#define NT 8192
#define DM 1024
#define NE 8
#define MAX_TILES 160
#define SLOTS_MAX 17408   // 16384 + 8*128 padding
#define NKT 32            // K-tiles of 32

typedef __bf16 bf16x8 __attribute__((ext_vector_type(8)));
typedef float f32x4 __attribute__((ext_vector_type(4)));
typedef float f32x16 __attribute__((ext_vector_type(16)));

typedef const __attribute__((address_space(1))) void* gp_t;
typedef __attribute__((address_space(3))) void* lp_t;
#define GLDS(g, l) __builtin_amdgcn_global_load_lds((gp_t)(g), (lp_t)(l), 16, 0, 0)

__device__ inline unsigned short f2bf(float f) {
  unsigned int u = __float_as_uint(f);
  unsigned int r = (u + 0x7fffu + ((u >> 16) & 1u)) >> 16;  // RNE
  return (unsigned short)r;
}
__device__ inline float bf2f(unsigned short u) {
  return __uint_as_float((unsigned int)u << 16);
}

// ---- prep: fused {expert-weight f32->bf16 cvt} + {router + per-block partial counts}. ----
__global__ void prep_kernel(const float* __restrict__ ew, unsigned short* __restrict__ wb,
                            const float* __restrict__ x, const float* __restrict__ gw,
                            float* __restrict__ logits, unsigned short* __restrict__ xb,
                            int* __restrict__ top2e, float* __restrict__ top2w,
                            int* __restrict__ pcount) {
  const int b = blockIdx.x;
  const int t = threadIdx.x;
  if (b < 4096) {
    size_t i = ((size_t)b * 256 + t) * 8;
    float4 a = *(const float4*)(ew + i);
    float4 c = *(const float4*)(ew + i + 4);
    union { unsigned short u[8]; uint4 v; } o;
    o.u[0] = f2bf(a.x); o.u[1] = f2bf(a.y); o.u[2] = f2bf(a.z); o.u[3] = f2bf(a.w);
    o.u[4] = f2bf(c.x); o.u[5] = f2bf(c.y); o.u[6] = f2bf(c.z); o.u[7] = f2bf(c.w);
    *(uint4*)(wb + i) = o.v;
    return;
  }
  __shared__ int lcnt[NE];
  if (t < NE) lcnt[t] = 0;
  __syncthreads();
  const int lane = t & 63;
  const int n = (b - 4096) * 4 + (t >> 6);
  const float* xr = x + (size_t)n * DM;
  float s[NE];
#pragma unroll
  for (int e = 0; e < NE; ++e) s[e] = 0.f;
  for (int c = lane; c < DM; c += 64) {
    float xv = xr[c];
    xb[(size_t)n * DM + c] = f2bf(xv);
#pragma unroll
    for (int e = 0; e < NE; ++e) s[e] += xv * gw[e * DM + c];
  }
#pragma unroll
  for (int e = 0; e < NE; ++e) {
#pragma unroll
    for (int off = 32; off > 0; off >>= 1) s[e] += __shfl_xor(s[e], off);
  }
  if (lane == 0) {
    float m = s[0];
#pragma unroll
    for (int e = 1; e < NE; ++e) m = fmaxf(m, s[e]);
    float p[NE];
#pragma unroll
    for (int e = 0; e < NE; ++e) {
      p[e] = __expf(s[e] - m);
      logits[(size_t)n * NE + e] = s[e];
    }
    int e1 = 0; float b1 = p[0];
#pragma unroll
    for (int e = 1; e < NE; ++e) if (p[e] > b1) { b1 = p[e]; e1 = e; }
    int e2 = -1; float b2 = -1.f;
#pragma unroll
    for (int e = 0; e < NE; ++e) if (e != e1 && p[e] > b2) { b2 = p[e]; e2 = e; }
    float inv = 1.f / (b1 + b2);
    top2e[n * 2 + 0] = e1; top2e[n * 2 + 1] = e2;
    top2w[n * 2 + 0] = b1 * inv; top2w[n * 2 + 1] = b2 * inv;
    atomicAdd(&lcnt[e1], 1);       // LDS atomics only
    atomicAdd(&lcnt[e2], 1);
  }
  __syncthreads();
  if (t < NE) pcount[(b - 4096) * NE + t] = lcnt[t];
}

// ---- plan (1 block x 256): reduce partials, prefix sum (pad 128), tile table,
// zero counts2, zero slot_token padding. ----
__global__ void plan_kernel(const int* __restrict__ pcount,
                            int* __restrict__ seg_base, int* __restrict__ counts2,
                            int* __restrict__ tile_e, int* __restrict__ tile_row,
                            int* __restrict__ n_tiles, int* __restrict__ slot_token) {
  __shared__ int lcnt[NE];
  __shared__ int sb[NE + 1], tb[NE + 1], cnt[NE];
  const int t = threadIdx.x;
  if (t < NE) lcnt[t] = 0;
  __syncthreads();
  int s[NE];
#pragma unroll
  for (int e = 0; e < NE; ++e) s[e] = 0;
#pragma unroll
  for (int i = 0; i < 8; ++i) {
    const int* p = pcount + (t + 256 * i) * NE;
#pragma unroll
    for (int e = 0; e < NE; ++e) s[e] += p[e];
  }
#pragma unroll
  for (int e = 0; e < NE; ++e) {
#pragma unroll
    for (int off = 32; off > 0; off >>= 1) s[e] += __shfl_xor(s[e], off);
  }
  if ((t & 63) == 0) {
#pragma unroll
    for (int e = 0; e < NE; ++e) atomicAdd(&lcnt[e], s[e]);
  }
  __syncthreads();
  if (t == 0) {
    int base = 0, tt = 0;
    for (int e = 0; e < NE; ++e) {
      sb[e] = base; tb[e] = tt;
      const int c = lcnt[e];
      cnt[e] = c;
      const int nt = (c + 127) >> 7;
      tt += nt;
      base += nt << 7;
    }
    sb[NE] = base; tb[NE] = tt;
    *n_tiles = tt;
  }
  __syncthreads();
  if (t <= NE) seg_base[t] = sb[t];
  if (t < NE) counts2[t] = 0;
  const int total = tb[NE];
  for (int i = t; i < total; i += 256) {
    int e = 0;
#pragma unroll
    for (int q = 0; q < NE; ++q) if (i >= tb[q + 1]) e = q + 1;
    tile_e[i] = e;
    tile_row[i] = sb[e] + (i - tb[e]) * 128;
  }
  for (int i = t; i < NE * 128; i += 256) {
    const int e = i >> 7, off = i & 127;
    const int pos = sb[e] + cnt[e] + off;
    if (pos < sb[e + 1]) slot_token[pos] = 0;
  }
}

// ---------------- scatter: block-aggregated segment claim; builds tok2slot ----------------
__global__ void scatter_kernel(const int* __restrict__ top2e,
                               const int* __restrict__ seg_base, int* __restrict__ counts2,
                               int* __restrict__ slot_token, int* __restrict__ tok2slot) {
  __shared__ int lcnt[NE], lbase[NE];
  const int t = threadIdx.x;
  if (t < NE) lcnt[t] = 0;
  __syncthreads();
  const int n = blockIdx.x * 256 + t;
  const int e0 = top2e[n * 2 + 0], e1 = top2e[n * 2 + 1];
  const int p0 = atomicAdd(&lcnt[e0], 1);
  const int p1 = atomicAdd(&lcnt[e1], 1);
  __syncthreads();
  if (t < NE) lbase[t] = seg_base[t] + atomicAdd(&counts2[t], lcnt[t]);
  __syncthreads();
  const int q0 = lbase[e0] + p0, q1 = lbase[e1] + p1;
  slot_token[q0] = n; slot_token[q1] = n;
  tok2slot[n * 2 + 0] = q0;
  tok2slot[n * 2 + 1] = q1;
}

// ---- grouped GEMM v2: BM=128 x BN=256, 4 waves (wave w owns cols w*64), BK=32,
// mfma_f32_32x32x16_bf16 (wave tile 128x64 -> FLOP/LDS-read-byte 42.7 vs 32).
// LDS 48KB dbuf -> 2 blocks/CU. R6-verified row-pair swizzle (64B rows packed in
// 128B lines, s_p = s ^ (L&7)); R5-style 2-barrier counted-vmcnt(6) pipeline.
__global__ __launch_bounds__(256, 2) void moe_gemm_kernel(
    const unsigned short* __restrict__ xb,   // [NT][DM] bf16
    const unsigned short* __restrict__ wb,   // [NE][DM][DM] bf16
    const float* __restrict__ bias,          // [NE][DM] f32
    const int* __restrict__ slot_token,
    const int* __restrict__ tile_e, const int* __restrict__ tile_row,
    const int* __restrict__ n_tiles,
    unsigned short* __restrict__ y)          // [SLOTS_MAX][DM] bf16
{
  // XCD-chunked swizzle: grid 640 = 8 XCDs x 80; same-bm blocks share an XCD's L2.
  const int bid = blockIdx.x;
  const int swz = (bid & 7) * 80 + (bid >> 3);
  const int bm = swz >> 2;
  const int bn = swz & 3;
  if (bm >= *n_tiles) return;
  const int e = tile_e[bm];
  const int row0 = tile_row[bm];
  const int n0 = bn * 256;

  __shared__ __align__(16) unsigned short lA[2][4096];   // 2 x 8KB  (128 rows x 32)
  __shared__ __align__(16) unsigned short lB[2][8192];   // 2 x 16KB (256 rows x 32)

  const int t = threadIdx.x;
  const int lane = t & 63;
  const int w = t >> 6;              // wave owns cols w*64

  // Staging inverse map (R6-verified 0-conflict): chunk c -> phys byte c*4096 + t*16;
  // L = c*32 + (t>>3); s = (t&7) ^ (L&7); row = 2L + (s>>2); kslot = s&3.
  const int sS = (t & 7) ^ ((t >> 3) & 7);
  const unsigned short* asrc[2];
  const unsigned short* bsrc[4];
#pragma unroll
  for (int c = 0; c < 2; ++c) {
    const int lr = c * 64 + ((t >> 3) << 1) + (sS >> 2);
    const int tok = slot_token[row0 + lr];          // padded rows -> token 0
    asrc[c] = xb + (size_t)tok * DM + (sS & 3) * 8;
  }
#pragma unroll
  for (int c = 0; c < 4; ++c) {
    const int lr = c * 64 + ((t >> 3) << 1) + (sS >> 2);
    bsrc[c] = wb + (size_t)e * DM * DM + (size_t)(n0 + lr) * DM + (sS & 3) * 8;
  }

  f32x16 acc[4][2];
#pragma unroll
  for (int i = 0; i < 4; ++i)
#pragma unroll
    for (int j = 0; j < 2; ++j)
#pragma unroll
      for (int v = 0; v < 16; ++v) acc[i][j][v] = 0.f;

  auto stage = [&](int buf, int kt) {   // 6 GLDS/thread
    const int ko = kt * 32;
    GLDS(asrc[0] + ko, &lA[buf][t * 8]);
    GLDS(asrc[1] + ko, &lA[buf][2048 + t * 8]);
#pragma unroll
    for (int c = 0; c < 4; ++c)
      GLDS(bsrc[c] + ko, &lB[buf][c * 2048 + t * 8]);
  };

  stage(0, 0);
  stage(1, 1);

  const int l31 = lane & 31;
  const int khalf = lane >> 5;       // 0..1 -> k-offset 8 within each K=16 group
  // LDS byte offset for row r, 16B k-slot q (R6-verified read map):
  //   (r>>1)*128 + ((((r&1)<<2)|q) ^ ((r>>1)&7))*16
  for (int kt = 0; kt < NKT; ++kt) {
    if (kt < NKT - 1) {
      asm volatile("s_waitcnt vmcnt(6)" ::: "memory");
    } else {
      asm volatile("s_waitcnt vmcnt(0)" ::: "memory");
    }
    __builtin_amdgcn_sched_barrier(0);
    __builtin_amdgcn_s_barrier();            // all waves' tile-kt loads in LDS

    const int cur = kt & 1;
    bf16x8 af[2][4], bf[2][2];
#pragma unroll
    for (int kg = 0; kg < 2; ++kg) {         // K=16 groups within BK=32
      const int q = kg * 2 + khalf;          // 16B k-slot 0..3
#pragma unroll
      for (int mb = 0; mb < 4; ++mb) {       // 32-row blocks of A
        const int r = mb * 32 + l31;
        const int off = (r >> 1) * 128 + (((((r & 1) << 2) | q) ^ ((r >> 1) & 7)) << 4);
        af[kg][mb] = *(const bf16x8*)((const char*)lA[cur] + off);
      }
#pragma unroll
      for (int nb = 0; nb < 2; ++nb) {       // 32-col blocks within wave's 64 cols
        const int r = w * 64 + nb * 32 + l31;
        const int off = (r >> 1) * 128 + (((((r & 1) << 2) | q) ^ ((r >> 1) & 7)) << 4);
        bf[kg][nb] = *(const bf16x8*)((const char*)lB[cur] + off);
      }
    }
    __builtin_amdgcn_s_setprio(1);
#pragma unroll
    for (int kg = 0; kg < 2; ++kg)
#pragma unroll
      for (int mb = 0; mb < 4; ++mb)
#pragma unroll
        for (int nb = 0; nb < 2; ++nb)
          acc[mb][nb] = __builtin_amdgcn_mfma_f32_32x32x16_bf16(af[kg][mb], bf[kg][nb], acc[mb][nb], 0, 0, 0);
    __builtin_amdgcn_s_setprio(0);

    __builtin_amdgcn_sched_barrier(0);
    __builtin_amdgcn_s_barrier();            // all waves done reading buf cur
    if (kt + 2 < NKT) stage(cur, kt + 2);    // refill the buffer just freed
  }

  // Epilogue: C/D 32x32 layout (m74/m101): col = lane&31, row = (reg&3)+8*(reg>>2)+4*(lane>>5).
  const int colb = n0 + w * 64;
  float bv[2];
#pragma unroll
  for (int nb = 0; nb < 2; ++nb)
    bv[nb] = bias[e * DM + colb + nb * 32 + l31];
#pragma unroll
  for (int mb = 0; mb < 4; ++mb) {
#pragma unroll
    for (int reg = 0; reg < 16; ++reg) {
      const int r = row0 + mb * 32 + (reg & 3) + 8 * (reg >> 2) + 4 * khalf;
      unsigned short* yrow = y + (size_t)r * DM + colb;
#pragma unroll
      for (int nb = 0; nb < 2; ++nb)
        yrow[nb * 32 + l31] = f2bf(acc[mb][nb][reg] + bv[nb]);
    }
  }
}

// ---------------- combine: out[n] = w0*y[s0] + w1*y[s1] ----------------
__global__ void combine_kernel(const unsigned short* __restrict__ y,
                               const int* __restrict__ tok2slot,
                               const float* __restrict__ top2w,
                               float* __restrict__ out) {
  const int n = blockIdx.x;
  const int c = threadIdx.x;                       // 256 threads x 4 cols
  const int s0 = tok2slot[n * 2 + 0], s1 = tok2slot[n * 2 + 1];
  const float w0 = top2w[n * 2 + 0], w1 = top2w[n * 2 + 1];
  ushort4 a = *(const ushort4*)(y + (size_t)s0 * DM + c * 4);
  ushort4 b = *(const ushort4*)(y + (size_t)s1 * DM + c * 4);
  float4 r;
  r.x = w0 * bf2f(a.x) + w1 * bf2f(b.x);
  r.y = w0 * bf2f(a.y) + w1 * bf2f(b.y);
  r.z = w0 * bf2f(a.z) + w1 * bf2f(b.z);
  r.w = w0 * bf2f(a.w) + w1 * bf2f(b.w);
  *(float4*)(out + (size_t)n * DM + c * 4) = r;
}

extern "C" void kernel_launch(void* const* d_in, const int* in_sizes, int n_in,
                              void* d_out, int out_size, void* d_ws, size_t ws_size,
                              hipStream_t stream) {
  const float* x  = (const float*)d_in[0];
  const float* gw = (const float*)d_in[1];
  const float* ew = (const float*)d_in[2];
  const float* eb = (const float*)d_in[3];
  float* out    = (float*)d_out;                 // final [NT*DM]
  float* logits = out + (size_t)NT * DM;         // [NT*NE]

  char* ws = (char*)d_ws;
  int*   counts2    = (int*)(ws + 64);                   // 8
  int*   seg_base   = (int*)(ws + 128);                  // 9
  int*   n_tiles    = (int*)(ws + 192);                  // 1
  int*   tile_e     = (int*)(ws + 256);                  // <=160
  int*   tile_row   = (int*)(ws + 1024);                 // <=160
  int*   top2e      = (int*)(ws + 2048);                 // 16384 ints
  float* top2w      = (float*)(ws + 67584);              // 16384 f32
  int*   slot_token = (int*)(ws + 133120);               // SLOTS_MAX ints
  int*   tok2slot   = (int*)(ws + 202752);               // 16384 ints
  int*   pcount     = (int*)(ws + 268288);               // 2048*8 ints (64KB)
  unsigned short* xb = (unsigned short*)(ws + 335872);                      // 16 MB
  unsigned short* wb = (unsigned short*)(ws + 335872 + 16777216);           // 16 MB
  unsigned short* y  = (unsigned short*)(ws + 335872 + 2 * 16777216);       // ~35 MB

  prep_kernel<<<4096 + NT / 4, 256, 0, stream>>>(ew, wb, x, gw, logits, xb,
                                                 top2e, top2w, pcount);
  plan_kernel<<<1, 256, 0, stream>>>(pcount, seg_base, counts2, tile_e, tile_row,
                                     n_tiles, slot_token);
  scatter_kernel<<<NT / 256, 256, 0, stream>>>(top2e, seg_base, counts2, slot_token, tok2slot);
  moe_gemm_kernel<<<MAX_TILES * 4, 256, 0, stream>>>(xb, wb, eb, slot_token,
                                                     tile_e, tile_row, n_tiles, y);
  combine_kernel<<<NT, 256, 0, stream>>>(y, tok2slot, top2w, out);
}

// Round 13
// 109.047 us; speedup vs baseline: 1.0630x; 1.0630x over previous
//
#include <hip/hip_runtime.h>
#include <hip/hip_bf16.h>
#include <stdint.h>

#define NT 8192
#define DM 1024
#define NE 8
#define MAX_TILES 160
#define SLOTS_MAX 17408   // 16384 + 8*128 padding
#define NKT 32            // K-tiles of 32

typedef __bf16 bf16x8 __attribute__((ext_vector_type(8)));
typedef float f32x4 __attribute__((ext_vector_type(4)));

typedef const __attribute__((address_space(1))) void* gp_t;
typedef __attribute__((address_space(3))) void* lp_t;
#define GLDS(g, l) __builtin_amdgcn_global_load_lds((gp_t)(g), (lp_t)(l), 16, 0, 0)

__device__ inline unsigned short f2bf(float f) {
  unsigned int u = __float_as_uint(f);
  unsigned int r = (u + 0x7fffu + ((u >> 16) & 1u)) >> 16;  // RNE
  return (unsigned short)r;
}
__device__ inline float bf2f(unsigned short u) {
  return __uint_as_float((unsigned int)u << 16);
}

// ---- prep: fused {expert-weight f32->bf16 cvt} + {router + per-block partial counts}. ----
__global__ void prep_kernel(const float* __restrict__ ew, unsigned short* __restrict__ wb,
                            const float* __restrict__ x, const float* __restrict__ gw,
                            float* __restrict__ logits, unsigned short* __restrict__ xb,
                            int* __restrict__ top2e, float* __restrict__ top2w,
                            int* __restrict__ pcount) {
  const int b = blockIdx.x;
  const int t = threadIdx.x;
  if (b < 4096) {
    size_t i = ((size_t)b * 256 + t) * 8;
    float4 a = *(const float4*)(ew + i);
    float4 c = *(const float4*)(ew + i + 4);
    union { unsigned short u[8]; uint4 v; } o;
    o.u[0] = f2bf(a.x); o.u[1] = f2bf(a.y); o.u[2] = f2bf(a.z); o.u[3] = f2bf(a.w);
    o.u[4] = f2bf(c.x); o.u[5] = f2bf(c.y); o.u[6] = f2bf(c.z); o.u[7] = f2bf(c.w);
    *(uint4*)(wb + i) = o.v;
    return;
  }
  __shared__ int lcnt[NE];
  if (t < NE) lcnt[t] = 0;
  __syncthreads();
  const int lane = t & 63;
  const int n = (b - 4096) * 4 + (t >> 6);
  const float* xr = x + (size_t)n * DM;
  float s[NE];
#pragma unroll
  for (int e = 0; e < NE; ++e) s[e] = 0.f;
  for (int c = lane; c < DM; c += 64) {
    float xv = xr[c];
    xb[(size_t)n * DM + c] = f2bf(xv);
#pragma unroll
    for (int e = 0; e < NE; ++e) s[e] += xv * gw[e * DM + c];
  }
#pragma unroll
  for (int e = 0; e < NE; ++e) {
#pragma unroll
    for (int off = 32; off > 0; off >>= 1) s[e] += __shfl_xor(s[e], off);
  }
  if (lane == 0) {
    float m = s[0];
#pragma unroll
    for (int e = 1; e < NE; ++e) m = fmaxf(m, s[e]);
    float p[NE];
#pragma unroll
    for (int e = 0; e < NE; ++e) {
      p[e] = __expf(s[e] - m);
      logits[(size_t)n * NE + e] = s[e];
    }
    int e1 = 0; float b1 = p[0];
#pragma unroll
    for (int e = 1; e < NE; ++e) if (p[e] > b1) { b1 = p[e]; e1 = e; }
    int e2 = -1; float b2 = -1.f;
#pragma unroll
    for (int e = 0; e < NE; ++e) if (e != e1 && p[e] > b2) { b2 = p[e]; e2 = e; }
    float inv = 1.f / (b1 + b2);
    top2e[n * 2 + 0] = e1; top2e[n * 2 + 1] = e2;
    top2w[n * 2 + 0] = b1 * inv; top2w[n * 2 + 1] = b2 * inv;
    atomicAdd(&lcnt[e1], 1);       // LDS atomics only
    atomicAdd(&lcnt[e2], 1);
  }
  __syncthreads();
  if (t < NE) pcount[(b - 4096) * NE + t] = lcnt[t];
}

// ---- plan (1 block x 256): reduce partials, prefix sum (pad 128), tile table,
// zero counts2, zero slot_token padding. ----
__global__ void plan_kernel(const int* __restrict__ pcount,
                            int* __restrict__ seg_base, int* __restrict__ counts2,
                            int* __restrict__ tile_e, int* __restrict__ tile_row,
                            int* __restrict__ n_tiles, int* __restrict__ slot_token) {
  __shared__ int lcnt[NE];
  __shared__ int sb[NE + 1], tb[NE + 1], cnt[NE];
  const int t = threadIdx.x;
  if (t < NE) lcnt[t] = 0;
  __syncthreads();
  int s[NE];
#pragma unroll
  for (int e = 0; e < NE; ++e) s[e] = 0;
#pragma unroll
  for (int i = 0; i < 8; ++i) {
    const int* p = pcount + (t + 256 * i) * NE;
#pragma unroll
    for (int e = 0; e < NE; ++e) s[e] += p[e];
  }
#pragma unroll
  for (int e = 0; e < NE; ++e) {
#pragma unroll
    for (int off = 32; off > 0; off >>= 1) s[e] += __shfl_xor(s[e], off);
  }
  if ((t & 63) == 0) {
#pragma unroll
    for (int e = 0; e < NE; ++e) atomicAdd(&lcnt[e], s[e]);
  }
  __syncthreads();
  if (t == 0) {
    int base = 0, tt = 0;
    for (int e = 0; e < NE; ++e) {
      sb[e] = base; tb[e] = tt;
      const int c = lcnt[e];
      cnt[e] = c;
      const int nt = (c + 127) >> 7;
      tt += nt;
      base += nt << 7;
    }
    sb[NE] = base; tb[NE] = tt;
    *n_tiles = tt;
  }
  __syncthreads();
  if (t <= NE) seg_base[t] = sb[t];
  if (t < NE) counts2[t] = 0;
  const int total = tb[NE];
  for (int i = t; i < total; i += 256) {
    int e = 0;
#pragma unroll
    for (int q = 0; q < NE; ++q) if (i >= tb[q + 1]) e = q + 1;
    tile_e[i] = e;
    tile_row[i] = sb[e] + (i - tb[e]) * 128;
  }
  for (int i = t; i < NE * 128; i += 256) {
    const int e = i >> 7, off = i & 127;
    const int pos = sb[e] + cnt[e] + off;
    if (pos < sb[e + 1]) slot_token[pos] = 0;
  }
}

// ---------------- scatter: block-aggregated segment claim; builds tok2slot ----------------
__global__ void scatter_kernel(const int* __restrict__ top2e,
                               const int* __restrict__ seg_base, int* __restrict__ counts2,
                               int* __restrict__ slot_token, int* __restrict__ tok2slot) {
  __shared__ int lcnt[NE], lbase[NE];
  const int t = threadIdx.x;
  if (t < NE) lcnt[t] = 0;
  __syncthreads();
  const int n = blockIdx.x * 256 + t;
  const int e0 = top2e[n * 2 + 0], e1 = top2e[n * 2 + 1];
  const int p0 = atomicAdd(&lcnt[e0], 1);
  const int p1 = atomicAdd(&lcnt[e1], 1);
  __syncthreads();
  if (t < NE) lbase[t] = seg_base[t] + atomicAdd(&counts2[t], lcnt[t]);
  __syncthreads();
  const int q0 = lbase[e0] + p0, q1 = lbase[e1] + p1;
  slot_token[q0] = n; slot_token[q1] = n;
  tok2slot[n * 2 + 0] = q0;
  tok2slot[n * 2 + 1] = q1;
}

// ---- grouped GEMM v3: BM=128 x BN=256, 4 waves, wave tile 128x64 (8 M-frags x 4 N-frags),
// BK=32, 16x16x32 MFMA (keeps the VERIFIED conflict-free q=lane>>4 full-line read map).
// LDS reads/FLOP -25% vs R11. 48KB dbuf -> 2 blocks/CU. R6 row-pair swizzle byte-identical.
// R5-style 2-barrier counted-vmcnt pipeline (6 GLDS/stage -> vmcnt(6)).
__global__ __launch_bounds__(256, 2) void moe_gemm_kernel(
    const unsigned short* __restrict__ xb,   // [NT][DM] bf16
    const unsigned short* __restrict__ wb,   // [NE][DM][DM] bf16
    const float* __restrict__ bias,          // [NE][DM] f32
    const int* __restrict__ slot_token,
    const int* __restrict__ tile_e, const int* __restrict__ tile_row,
    const int* __restrict__ n_tiles,
    unsigned short* __restrict__ y)          // [SLOTS_MAX][DM] bf16
{
  // XCD-chunked swizzle: grid 640 = 8 XCDs x 80; same-bm blocks share an XCD's L2.
  const int bid = blockIdx.x;
  const int swz = (bid & 7) * 80 + (bid >> 3);
  const int bm = swz >> 2;
  const int bn = swz & 3;
  if (bm >= *n_tiles) return;
  const int e = tile_e[bm];
  const int row0 = tile_row[bm];
  const int n0 = bn * 256;

  __shared__ __align__(16) unsigned short lA[2][4096];   // 2 x 8KB  (128 rows x 32)
  __shared__ __align__(16) unsigned short lB[2][8192];   // 2 x 16KB (256 rows x 32)

  const int t = threadIdx.x;
  const int lane = t & 63;
  const int w = t >> 6;              // wave owns cols n0 + w*64

  // Staging inverse map (R6-verified 0-conflict): chunk c -> phys byte c*4096 + t*16;
  // L = c*32 + (t>>3); s = (t&7) ^ (L&7); row = 2L + (s>>2); kslot = s&3.
  const int sS = (t & 7) ^ ((t >> 3) & 7);
  const unsigned short* asrc[2];
  const unsigned short* bsrc[4];
#pragma unroll
  for (int c = 0; c < 2; ++c) {
    const int lr = c * 64 + ((t >> 3) << 1) + (sS >> 2);
    const int tok = slot_token[row0 + lr];          // padded rows -> token 0
    asrc[c] = xb + (size_t)tok * DM + (sS & 3) * 8;
  }
#pragma unroll
  for (int c = 0; c < 4; ++c) {
    const int lr = c * 64 + ((t >> 3) << 1) + (sS >> 2);
    bsrc[c] = wb + (size_t)e * DM * DM + (size_t)(n0 + lr) * DM + (sS & 3) * 8;
  }

  f32x4 acc[8][4];
#pragma unroll
  for (int i = 0; i < 8; ++i)
#pragma unroll
    for (int j = 0; j < 4; ++j) acc[i][j] = (f32x4){0.f, 0.f, 0.f, 0.f};

  auto stage = [&](int buf, int kt) {   // 6 GLDS/thread
    const int ko = kt * 32;
    GLDS(asrc[0] + ko, &lA[buf][t * 8]);
    GLDS(asrc[1] + ko, &lA[buf][2048 + t * 8]);
#pragma unroll
    for (int c = 0; c < 4; ++c)
      GLDS(bsrc[c] + ko, &lB[buf][c * 2048 + t * 8]);
  };

  stage(0, 0);
  stage(1, 1);

  const int q = lane >> 4;           // 16B k-slot 0..3 (FULL line coverage per wave)
  const int l15 = lane & 15;
  // LDS byte offset for row r, k-slot q (R6-verified read map):
  //   (r>>1)*128 + ((((r&1)<<2)|q) ^ ((r>>1)&7))*16
  for (int kt = 0; kt < NKT; ++kt) {
    if (kt < NKT - 1) {
      asm volatile("s_waitcnt vmcnt(6)" ::: "memory");
    } else {
      asm volatile("s_waitcnt vmcnt(0)" ::: "memory");
    }
    __builtin_amdgcn_sched_barrier(0);
    __builtin_amdgcn_s_barrier();            // all waves' tile-kt loads in LDS

    const int cur = kt & 1;
    bf16x8 af[8], bf[4];
#pragma unroll
    for (int mi = 0; mi < 8; ++mi) {
      const int r = mi * 16 + l15;
      const int off = (r >> 1) * 128 + (((((r & 1) << 2) | q) ^ ((r >> 1) & 7)) << 4);
      af[mi] = *(const bf16x8*)((const char*)lA[cur] + off);
    }
#pragma unroll
    for (int ni = 0; ni < 4; ++ni) {
      const int r = w * 64 + ni * 16 + l15;
      const int off = (r >> 1) * 128 + (((((r & 1) << 2) | q) ^ ((r >> 1) & 7)) << 4);
      bf[ni] = *(const bf16x8*)((const char*)lB[cur] + off);
    }
    __builtin_amdgcn_s_setprio(1);
#pragma unroll
    for (int mi = 0; mi < 8; ++mi)
#pragma unroll
      for (int ni = 0; ni < 4; ++ni)
        acc[mi][ni] = __builtin_amdgcn_mfma_f32_16x16x32_bf16(af[mi], bf[ni], acc[mi][ni], 0, 0, 0);
    __builtin_amdgcn_s_setprio(0);

    __builtin_amdgcn_sched_barrier(0);
    __builtin_amdgcn_s_barrier();            // all waves done reading buf cur
    if (kt + 2 < NKT) stage(cur, kt + 2);    // refill the buffer just freed
  }

  // Epilogue: bias add, plain coalesced bf16 stores into y.
  const int cgrp = lane >> 4, ccol = lane & 15;
  const int colb = n0 + w * 64;
  float bv[4];
#pragma unroll
  for (int ni = 0; ni < 4; ++ni)
    bv[ni] = bias[e * DM + colb + ni * 16 + ccol];
#pragma unroll
  for (int mi = 0; mi < 8; ++mi) {
#pragma unroll
    for (int j = 0; j < 4; ++j) {
      const int r = row0 + mi * 16 + cgrp * 4 + j;
      unsigned short* yrow = y + (size_t)r * DM + colb;
#pragma unroll
      for (int ni = 0; ni < 4; ++ni)
        yrow[ni * 16 + ccol] = f2bf(acc[mi][ni][j] + bv[ni]);
    }
  }
}

// ---------------- combine: out[n] = w0*y[s0] + w1*y[s1] ----------------
__global__ void combine_kernel(const unsigned short* __restrict__ y,
                               const int* __restrict__ tok2slot,
                               const float* __restrict__ top2w,
                               float* __restrict__ out) {
  const int n = blockIdx.x;
  const int c = threadIdx.x;                       // 256 threads x 4 cols
  const int s0 = tok2slot[n * 2 + 0], s1 = tok2slot[n * 2 + 1];
  const float w0 = top2w[n * 2 + 0], w1 = top2w[n * 2 + 1];
  ushort4 a = *(const ushort4*)(y + (size_t)s0 * DM + c * 4);
  ushort4 b = *(const ushort4*)(y + (size_t)s1 * DM + c * 4);
  float4 r;
  r.x = w0 * bf2f(a.x) + w1 * bf2f(b.x);
  r.y = w0 * bf2f(a.y) + w1 * bf2f(b.y);
  r.z = w0 * bf2f(a.z) + w1 * bf2f(b.z);
  r.w = w0 * bf2f(a.w) + w1 * bf2f(b.w);
  *(float4*)(out + (size_t)n * DM + c * 4) = r;
}

extern "C" void kernel_launch(void* const* d_in, const int* in_sizes, int n_in,
                              void* d_out, int out_size, void* d_ws, size_t ws_size,
                              hipStream_t stream) {
  const float* x  = (const float*)d_in[0];
  const float* gw = (const float*)d_in[1];
  const float* ew = (const float*)d_in[2];
  const float* eb = (const float*)d_in[3];
  float* out    = (float*)d_out;                 // final [NT*DM]
  float* logits = out + (size_t)NT * DM;         // [NT*NE]

  char* ws = (char*)d_ws;
  int*   counts2    = (int*)(ws + 64);                   // 8
  int*   seg_base   = (int*)(ws + 128);                  // 9
  int*   n_tiles    = (int*)(ws + 192);                  // 1
  int*   tile_e     = (int*)(ws + 256);                  // <=160
  int*   tile_row   = (int*)(ws + 1024);                 // <=160
  int*   top2e      = (int*)(ws + 2048);                 // 16384 ints
  float* top2w      = (float*)(ws + 67584);              // 16384 f32
  int*   slot_token = (int*)(ws + 133120);               // SLOTS_MAX ints
  int*   tok2slot   = (int*)(ws + 202752);               // 16384 ints
  int*   pcount     = (int*)(ws + 268288);               // 2048*8 ints (64KB)
  unsigned short* xb = (unsigned short*)(ws + 335872);                      // 16 MB
  unsigned short* wb = (unsigned short*)(ws + 335872 + 16777216);           // 16 MB
  unsigned short* y  = (unsigned short*)(ws + 335872 + 2 * 16777216);       // ~35 MB

  prep_kernel<<<4096 + NT / 4, 256, 0, stream>>>(ew, wb, x, gw, logits, xb,
                                                 top2e, top2w, pcount);
  plan_kernel<<<1, 256, 0, stream>>>(pcount, seg_base, counts2, tile_e, tile_row,
                                     n_tiles, slot_token);
  scatter_kernel<<<NT / 256, 256, 0, stream>>>(top2e, seg_base, counts2, slot_token, tok2slot);
  moe_gemm_kernel<<<MAX_TILES * 4, 256, 0, stream>>>(xb, wb, eb, slot_token,
                                                     tile_e, tile_row, n_tiles, y);
  combine_kernel<<<NT, 256, 0, stream>>>(y, tok2slot, top2w, out);
}

// Round 14
// 97.771 us; speedup vs baseline: 1.1856x; 1.1153x over previous
//
#include <hip/hip_runtime.h>
#include <hip/hip_bf16.h>
#include <stdint.h>

#define NT 8192
#define DM 1024
#define NE 8
#define MAX_TILES 160
#define SLOTS_MAX 17408   // 16384 + 8*128 padding
#define NKT (DM / 64)     // 16 K-tiles of 64

typedef __bf16 bf16x8 __attribute__((ext_vector_type(8)));
typedef float f32x4 __attribute__((ext_vector_type(4)));

typedef const __attribute__((address_space(1))) void* gp_t;
typedef __attribute__((address_space(3))) void* lp_t;
#define GLDS(g, l) __builtin_amdgcn_global_load_lds((gp_t)(g), (lp_t)(l), 16, 0, 0)

__device__ inline unsigned short f2bf(float f) {
  unsigned int u = __float_as_uint(f);
  unsigned int r = (u + 0x7fffu + ((u >> 16) & 1u)) >> 16;  // RNE
  return (unsigned short)r;
}
__device__ inline float bf2f(unsigned short u) {
  return __uint_as_float((unsigned int)u << 16);
}

// ---- prep: fused {expert-weight f32->bf16 cvt} + {router + per-block partial counts}.
// Block 0 also zeroes counts2 (needed by scatter, next launch). ----
__global__ void prep_kernel(const float* __restrict__ ew, unsigned short* __restrict__ wb,
                            const float* __restrict__ x, const float* __restrict__ gw,
                            float* __restrict__ logits, unsigned short* __restrict__ xb,
                            int* __restrict__ top2e, float* __restrict__ top2w,
                            int* __restrict__ pcount, int* __restrict__ counts2) {
  const int b = blockIdx.x;
  const int t = threadIdx.x;
  if (b < 4096) {
    if (b == 0 && t < NE) counts2[t] = 0;
    size_t i = ((size_t)b * 256 + t) * 8;
    float4 a = *(const float4*)(ew + i);
    float4 c = *(const float4*)(ew + i + 4);
    union { unsigned short u[8]; uint4 v; } o;
    o.u[0] = f2bf(a.x); o.u[1] = f2bf(a.y); o.u[2] = f2bf(a.z); o.u[3] = f2bf(a.w);
    o.u[4] = f2bf(c.x); o.u[5] = f2bf(c.y); o.u[6] = f2bf(c.z); o.u[7] = f2bf(c.w);
    *(uint4*)(wb + i) = o.v;
    return;
  }
  __shared__ int lcnt[NE];
  if (t < NE) lcnt[t] = 0;
  __syncthreads();
  const int lane = t & 63;
  const int n = (b - 4096) * 4 + (t >> 6);
  const float* xr = x + (size_t)n * DM;
  float s[NE];
#pragma unroll
  for (int e = 0; e < NE; ++e) s[e] = 0.f;
  for (int c = lane; c < DM; c += 64) {
    float xv = xr[c];
    xb[(size_t)n * DM + c] = f2bf(xv);
#pragma unroll
    for (int e = 0; e < NE; ++e) s[e] += xv * gw[e * DM + c];
  }
#pragma unroll
  for (int e = 0; e < NE; ++e) {
#pragma unroll
    for (int off = 32; off > 0; off >>= 1) s[e] += __shfl_xor(s[e], off);
  }
  if (lane == 0) {
    float m = s[0];
#pragma unroll
    for (int e = 1; e < NE; ++e) m = fmaxf(m, s[e]);
    float p[NE];
#pragma unroll
    for (int e = 0; e < NE; ++e) {
      p[e] = __expf(s[e] - m);
      logits[(size_t)n * NE + e] = s[e];
    }
    int e1 = 0; float b1 = p[0];
#pragma unroll
    for (int e = 1; e < NE; ++e) if (p[e] > b1) { b1 = p[e]; e1 = e; }
    int e2 = -1; float b2 = -1.f;
#pragma unroll
    for (int e = 0; e < NE; ++e) if (e != e1 && p[e] > b2) { b2 = p[e]; e2 = e; }
    float inv = 1.f / (b1 + b2);
    top2e[n * 2 + 0] = e1; top2e[n * 2 + 1] = e2;
    top2w[n * 2 + 0] = b1 * inv; top2w[n * 2 + 1] = b2 * inv;
    atomicAdd(&lcnt[e1], 1);       // LDS atomics only
    atomicAdd(&lcnt[e2], 1);
  }
  __syncthreads();
  if (t < NE) pcount[(b - 4096) * NE + t] = lcnt[t];
}

// ---- scatter (plan folded in): each of 32 blocks redundantly reduces pcount and
// computes the identical padded prefix sum (L2-hot, ~2MB aggregate). Block 0 alone
// writes n_tiles + tile tables and zeroes slot_token padding. Then the per-token
// block-aggregated segment claim as before. ----
__global__ void scatter_kernel(const int* __restrict__ top2e, const int* __restrict__ pcount,
                               int* __restrict__ counts2,
                               int* __restrict__ tile_e, int* __restrict__ tile_row,
                               int* __restrict__ n_tiles,
                               int* __restrict__ slot_token, int* __restrict__ tok2slot) {
  __shared__ int tot[NE];                  // global per-expert totals
  __shared__ int sb[NE + 1], tb[NE + 1];   // padded segment bases / tile bases
  __shared__ int lcnt[NE], lbase[NE];      // per-block claim
  const int t = threadIdx.x;
  if (t < NE) { tot[t] = 0; lcnt[t] = 0; }
  __syncthreads();
  // reduce pcount: thread t sums blocks t + 256*i (coalesced 32B/lane)
  int s[NE];
#pragma unroll
  for (int e = 0; e < NE; ++e) s[e] = 0;
#pragma unroll
  for (int i = 0; i < 8; ++i) {
    const int* p = pcount + (t + 256 * i) * NE;
#pragma unroll
    for (int e = 0; e < NE; ++e) s[e] += p[e];
  }
#pragma unroll
  for (int e = 0; e < NE; ++e) {
#pragma unroll
    for (int off = 32; off > 0; off >>= 1) s[e] += __shfl_xor(s[e], off);
  }
  if ((t & 63) == 0) {
#pragma unroll
    for (int e = 0; e < NE; ++e) atomicAdd(&tot[e], s[e]);
  }
  __syncthreads();
  if (t == 0) {
    int base = 0, tt = 0;
    for (int e = 0; e < NE; ++e) {
      sb[e] = base; tb[e] = tt;
      const int c = tot[e];
      const int nt = (c + 127) >> 7;
      tt += nt;
      base += nt << 7;              // segments padded to multiples of 128
    }
    sb[NE] = base; tb[NE] = tt;
  }
  __syncthreads();
  if (blockIdx.x == 0) {
    if (t == 0) *n_tiles = tb[NE];
    const int total = tb[NE];
    for (int i = t; i < total; i += 256) {
      int e = 0;
#pragma unroll
      for (int q = 0; q < NE; ++q) if (i >= tb[q + 1]) e = q + 1;
      tile_e[i] = e;
      tile_row[i] = sb[e] + (i - tb[e]) * 128;
    }
    for (int i = t; i < NE * 128; i += 256) {     // zero only padding slots
      const int e = i >> 7, off = i & 127;
      const int pos = sb[e] + tot[e] + off;
      if (pos < sb[e + 1]) slot_token[pos] = 0;
    }
  }
  // per-token claim
  const int n = blockIdx.x * 256 + t;
  const int e0 = top2e[n * 2 + 0], e1 = top2e[n * 2 + 1];
  const int p0 = atomicAdd(&lcnt[e0], 1);
  const int p1 = atomicAdd(&lcnt[e1], 1);
  __syncthreads();
  if (t < NE) lbase[t] = sb[t] + atomicAdd(&counts2[t], lcnt[t]);
  __syncthreads();
  const int q0 = lbase[e0] + p0, q1 = lbase[e1] + p1;
  slot_token[q0] = n; slot_token[q1] = n;
  tok2slot[n * 2 + 0] = q0;
  tok2slot[n * 2 + 1] = q1;
}

// ---- grouped GEMM (R11 bits, frozen — empirical optimum of this structure family):
// 128x128 tile, 4 waves, BK=64, GLDS + global-side XOR swizzle (0-conflict verified),
// 2-tile counted-vmcnt(8) pipeline, XCD-chunked block swizzle, bf16 y stores. ----
__global__ __launch_bounds__(256, 2) void moe_gemm_kernel(
    const unsigned short* __restrict__ xb,   // [NT][DM] bf16
    const unsigned short* __restrict__ wb,   // [NE][DM][DM] bf16
    const float* __restrict__ bias,          // [NE][DM] f32
    const int* __restrict__ slot_token,
    const int* __restrict__ tile_e, const int* __restrict__ tile_row,
    const int* __restrict__ n_tiles,
    unsigned short* __restrict__ y)          // [SLOTS_MAX][DM] bf16
{
  const int bid = blockIdx.x;
  const int swz = (bid & 7) * 160 + (bid >> 3);
  const int bm = swz >> 3;
  const int bn = swz & 7;
  if (bm >= *n_tiles) return;
  const int e = tile_e[bm];
  const int row0 = tile_row[bm];
  const int n0 = bn * 128;

  __shared__ __align__(16) unsigned short lA[2][8192];
  __shared__ __align__(16) unsigned short lB[2][8192];

  const int t = threadIdx.x;
  const int lane = t & 63;
  const int w = t >> 6;
  const int wm = w >> 1, wn = w & 1;

  const int srow = t >> 3;
  const int ss = (t & 7) ^ (srow & 7);
  const unsigned short* asrc[4];
  const unsigned short* bsrc[4];
#pragma unroll
  for (int c = 0; c < 4; ++c) {
    const int lr = c * 32 + srow;
    const int tok = slot_token[row0 + lr];          // padded rows -> token 0
    asrc[c] = xb + (size_t)tok * DM + ss * 8;
    bsrc[c] = wb + (size_t)e * DM * DM + (size_t)(n0 + lr) * DM + ss * 8;
  }

  f32x4 acc[4][4];
#pragma unroll
  for (int i = 0; i < 4; ++i)
#pragma unroll
    for (int j = 0; j < 4; ++j) acc[i][j] = (f32x4){0.f, 0.f, 0.f, 0.f};

  auto stage = [&](int buf, int kt) {
    const int ko = kt * 64;
#pragma unroll
    for (int c = 0; c < 4; ++c) {
      GLDS(asrc[c] + ko, &lA[buf][c * 2048 + w * 512]);
      GLDS(bsrc[c] + ko, &lB[buf][c * 2048 + w * 512]);
    }
  };

  stage(0, 0);
  stage(1, 1);

  for (int kt = 0; kt < NKT; ++kt) {
    if (kt < NKT - 1) {
      asm volatile("s_waitcnt vmcnt(8)" ::: "memory");
    } else {
      asm volatile("s_waitcnt vmcnt(0)" ::: "memory");
    }
    __builtin_amdgcn_sched_barrier(0);
    __builtin_amdgcn_s_barrier();            // all waves' tile-kt loads in LDS

    const int cur = kt & 1;
    bf16x8 af[2][4], bf[2][4];
#pragma unroll
    for (int ks = 0; ks < 2; ++ks) {
      const int kb = ks * 64 + (lane >> 4) * 16;   // K byte offset
#pragma unroll
      for (int mi = 0; mi < 4; ++mi) {
        const int row = wm * 64 + mi * 16 + (lane & 15);
        af[ks][mi] = *(const bf16x8*)((const char*)lA[cur] + row * 128 + (kb ^ ((row & 7) << 4)));
      }
#pragma unroll
      for (int ni = 0; ni < 4; ++ni) {
        const int row = wn * 64 + ni * 16 + (lane & 15);
        bf[ks][ni] = *(const bf16x8*)((const char*)lB[cur] + row * 128 + (kb ^ ((row & 7) << 4)));
      }
    }
    __builtin_amdgcn_s_setprio(1);
#pragma unroll
    for (int ks = 0; ks < 2; ++ks)
#pragma unroll
      for (int mi = 0; mi < 4; ++mi)
#pragma unroll
        for (int ni = 0; ni < 4; ++ni)
          acc[mi][ni] = __builtin_amdgcn_mfma_f32_16x16x32_bf16(af[ks][mi], bf[ks][ni], acc[mi][ni], 0, 0, 0);
    __builtin_amdgcn_s_setprio(0);

    __builtin_amdgcn_sched_barrier(0);
    __builtin_amdgcn_s_barrier();            // all waves done reading buf cur
    if (kt + 2 < NKT) stage(cur, kt + 2);    // refill the buffer just freed
  }

  const int cgrp = lane >> 4, ccol = lane & 15;
  float bv[4];
#pragma unroll
  for (int ni = 0; ni < 4; ++ni)
    bv[ni] = bias[e * DM + n0 + wn * 64 + ni * 16 + ccol];
#pragma unroll
  for (int mi = 0; mi < 4; ++mi) {
#pragma unroll
    for (int j = 0; j < 4; ++j) {
      const int r = row0 + wm * 64 + mi * 16 + cgrp * 4 + j;
      unsigned short* yrow = y + (size_t)r * DM + n0 + wn * 64;
#pragma unroll
      for (int ni = 0; ni < 4; ++ni)
        yrow[ni * 16 + ccol] = f2bf(acc[mi][ni][j] + bv[ni]);
    }
  }
}

// ---------------- combine: out[n] = w0*y[s0] + w1*y[s1] ----------------
__global__ void combine_kernel(const unsigned short* __restrict__ y,
                               const int* __restrict__ tok2slot,
                               const float* __restrict__ top2w,
                               float* __restrict__ out) {
  const int n = blockIdx.x;
  const int c = threadIdx.x;                       // 256 threads x 4 cols
  const int s0 = tok2slot[n * 2 + 0], s1 = tok2slot[n * 2 + 1];
  const float w0 = top2w[n * 2 + 0], w1 = top2w[n * 2 + 1];
  ushort4 a = *(const ushort4*)(y + (size_t)s0 * DM + c * 4);
  ushort4 b = *(const ushort4*)(y + (size_t)s1 * DM + c * 4);
  float4 r;
  r.x = w0 * bf2f(a.x) + w1 * bf2f(b.x);
  r.y = w0 * bf2f(a.y) + w1 * bf2f(b.y);
  r.z = w0 * bf2f(a.z) + w1 * bf2f(b.z);
  r.w = w0 * bf2f(a.w) + w1 * bf2f(b.w);
  *(float4*)(out + (size_t)n * DM + c * 4) = r;
}

extern "C" void kernel_launch(void* const* d_in, const int* in_sizes, int n_in,
                              void* d_out, int out_size, void* d_ws, size_t ws_size,
                              hipStream_t stream) {
  const float* x  = (const float*)d_in[0];
  const float* gw = (const float*)d_in[1];
  const float* ew = (const float*)d_in[2];
  const float* eb = (const float*)d_in[3];
  float* out    = (float*)d_out;                 // final [NT*DM]
  float* logits = out + (size_t)NT * DM;         // [NT*NE]

  char* ws = (char*)d_ws;
  int*   counts2    = (int*)(ws + 64);                   // 8
  int*   n_tiles    = (int*)(ws + 192);                  // 1
  int*   tile_e     = (int*)(ws + 256);                  // <=160
  int*   tile_row   = (int*)(ws + 1024);                 // <=160
  int*   top2e      = (int*)(ws + 2048);                 // 16384 ints
  float* top2w      = (float*)(ws + 67584);              // 16384 f32
  int*   slot_token = (int*)(ws + 133120);               // SLOTS_MAX ints
  int*   tok2slot   = (int*)(ws + 202752);               // 16384 ints
  int*   pcount     = (int*)(ws + 268288);               // 2048*8 ints (64KB)
  unsigned short* xb = (unsigned short*)(ws + 335872);                      // 16 MB
  unsigned short* wb = (unsigned short*)(ws + 335872 + 16777216);           // 16 MB
  unsigned short* y  = (unsigned short*)(ws + 335872 + 2 * 16777216);       // ~35 MB

  prep_kernel<<<4096 + NT / 4, 256, 0, stream>>>(ew, wb, x, gw, logits, xb,
                                                 top2e, top2w, pcount, counts2);
  scatter_kernel<<<NT / 256, 256, 0, stream>>>(top2e, pcount, counts2,
                                               tile_e, tile_row, n_tiles,
                                               slot_token, tok2slot);
  moe_gemm_kernel<<<MAX_TILES * 8, 256, 0, stream>>>(xb, wb, eb, slot_token,
                                                     tile_e, tile_row, n_tiles, y);
  combine_kernel<<<NT, 256, 0, stream>>>(y, tok2slot, top2w, out);
}